// Round 11
// baseline (368.911 us; speedup 1.0000x reference)
//
#include <hip/hip_runtime.h>
#include <hip/hip_bf16.h>
#include <stdint.h>

typedef __bf16 bf16_t;
typedef _Float16 f16_t;
typedef _Float16 f16x8 __attribute__((ext_vector_type(8)));
typedef float f32x4 __attribute__((ext_vector_type(4)));

#define HID 512
#define NRAW 736      // 32 * 23 (source layout)
#define NRAW_PAD 768  // 32 * 24 (channel-aligned: 23 coeffs + 1 zero pad)
#define TAILB 3.0f

__device__ __forceinline__ void glds16(const void* g, void* s) {
  __builtin_amdgcn_global_load_lds(
      (const __attribute__((address_space(1))) void*)g,
      (__attribute__((address_space(3))) void*)s, 16, 0, 0);
}
__device__ __forceinline__ float frcp(float x) { return __builtin_amdgcn_rcpf(x); }

// ---------------------------------------------------------------------------
__global__ void detect_dtype(const void* x, int* flag) {
  __shared__ int s;
  if (threadIdx.x == 0) s = 0;
  __syncthreads();
  const bf16_t* xb = (const bf16_t*)x;
  int cnt = 0;
  for (int j = 0; j < 16; j++) {
    float v = (float)xb[threadIdx.x * 16 + j];
    if (!(v == v) || fabsf(v) > 64.0f) cnt++;
  }
  atomicAdd(&s, cnt);
  __syncthreads();
  if (threadIdx.x == 0) *flag = (s > 64) ? 1 : 0;
}

// ---------------------------------------------------------------------------
__global__ void conv_wb(const void* W1, const void* W2, const void* W3,
                        const void* b1, const void* b2, const void* b3,
                        f16_t* __restrict__ w1t, f16_t* __restrict__ w2t,
                        f16_t* __restrict__ w3t,
                        float* __restrict__ bf1, float* __restrict__ bf2,
                        float* __restrict__ bf3, const int* flagp) {
  const int flag = *flagp;
  auto rd = [&](const void* p, size_t idx) -> float {
    return flag ? ((const float*)p)[idx] : (float)((const bf16_t*)p)[idx];
  };
  int i = blockIdx.x * 256 + threadIdx.x;
  if (i < 512 * 32)  { w1t[i] = (f16_t)rd(W1, (size_t)(i & 31) * 512 + (i >> 5)); return; }
  i -= 512 * 32;
  if (i < 512 * 512) { w2t[i] = (f16_t)rd(W2, (size_t)(i & 511) * 512 + (i >> 9)); return; }
  i -= 512 * 512;
  if (i < NRAW_PAD * 512) {
    int n = i >> 9, k = i & 511;
    int ch = n / 24, e = n % 24;
    w3t[i] = (e < 23) ? (f16_t)rd(W3, (size_t)k * NRAW + ch * 23 + e) : (f16_t)0.0f;
    return;
  }
  i -= NRAW_PAD * 512;
  if (i < 512) { bf1[i] = rd(b1, i); return; }
  i -= 512;
  if (i < 512) { bf2[i] = rd(b2, i); return; }
  i -= 512;
  if (i < NRAW_PAD) {
    int ch = i / 24, e = i % 24;
    bf3[i] = (e < 23) ? rd(b3, (size_t)ch * 23 + e) : 0.0f;
  }
}

// x ingest: masked half -> f16 (M x 32) AND masked passthrough -> out[:, :32].
__global__ void convert_x(const void* x, f16_t* __restrict__ xf,
                          void* __restrict__ outv, const int* flagp, int n) {
  const int flag = *flagp;
  const int i0 = (blockIdx.x * 256 + threadIdx.x) * 8;
  if (i0 >= n) return;
  const int row = i0 >> 5, col = i0 & 31;
  #pragma unroll
  for (int j = 0; j < 8; j++) {
    const size_t src = (size_t)row * 64 + col + j;
    float v = flag ? ((const float*)x)[src] : (float)((const bf16_t*)x)[src];
    xf[i0 + j] = (f16_t)v;
    if (flag) ((float*)outv)[src] = v;
    else      ((bf16_t*)outv)[src] = (bf16_t)v;
  }
}

__global__ void ld_finalize(const float* __restrict__ ldp, void* __restrict__ outv,
                            const int* __restrict__ flagp, int M) {
  const int i = blockIdx.x * 256 + threadIdx.x;
  if (i >= M) return;
  float s = 0.f;
  #pragma unroll
  for (int n = 0; n < 8; n++) s += ldp[(size_t)n * M + i];
  if (*flagp) ((float*)outv)[(size_t)M * 64 + i] = s;
  else        ((bf16_t*)outv)[(size_t)M * 64 + i] = (bf16_t)s;
}

// ---------------------------------------------------------------------------
// Fused GEMM1+GEMM2: h2 = relu(relu(X@W1+b1)@W2+b2). X: mc x 32 f16.
// h1 never touches HBM (LDS round trip with XOR swizzle). 3 barriers/iter.
// ---------------------------------------------------------------------------
__launch_bounds__(256)
__global__ void gemm12(const f16_t* __restrict__ X, const f16_t* __restrict__ W1t,
                       const float* __restrict__ b1, const f16_t* __restrict__ W2t,
                       const float* __restrict__ b2, f16_t* __restrict__ H2) {
  constexpr int BK = 64;
  __shared__ __align__(16) f16_t As[128 * BK], Bs[128 * BK];
  const int t = threadIdx.x;
  const int id = blockIdx.x;
  const int xcd = id & 7, s = id >> 3;
  const int n0 = (s & 3) * 128;
  const int m0 = ((s >> 2) * 8 + xcd) * 128;
  const int lrow = t >> 3, lcb = t & 7;
  const int lane = t & 63, w = t >> 6;
  const int wr = (w >> 1) * 64, wc = (w & 1) * 64, wc2 = (w & 1) * 32;
  const int lm = lane & 15, quad = lane >> 4;

  const f16_t* gb[4];
  f16_t* ldb[4];
  #pragma unroll
  for (int r = 0; r < 4; r++) {
    const int row = r * 32 + lrow;
    const int gc = (lcb ^ (row & 7)) * 8;
    gb[r] = W2t + (size_t)(n0 + row) * 512 + gc;
    ldb[r] = &Bs[row * BK + lcb * 8];
  }
  const f16x8* ap[4][2];
  const f16x8* bp[4][2];
  #pragma unroll
  for (int i = 0; i < 4; i++) {
    const int ra = wr + i * 16 + lm, rb = wc + i * 16 + lm;
    #pragma unroll
    for (int ksi = 0; ksi < 2; ksi++) {
      const int qb = ksi * 4 + quad;
      ap[i][ksi] = (const f16x8*)&As[ra * BK + ((qb ^ (ra & 7)) << 3)];
      bp[i][ksi] = (const f16x8*)&Bs[rb * BK + ((qb ^ (rb & 7)) << 3)];
    }
  }
  f16x8 xfr[4];
  #pragma unroll
  for (int i = 0; i < 4; i++)
    xfr[i] = *(const f16x8*)(X + (size_t)(m0 + wr + i * 16 + lm) * 32 + quad * 8);
  const f16_t* w1b0 = W1t + (size_t)(wc2 + lm) * 32 + quad * 8;
  const f16_t* w1b1 = W1t + (size_t)(wc2 + 16 + lm) * 32 + quad * 8;
  const float* b1b0 = b1 + wc2 + lm;
  const float* b1b1 = b1 + wc2 + 16 + lm;
  const int cb0 = (wc2 + lm) >> 3, lw = lm & 7;
  int rbase[4], xt0[4], xt1[4];
  #pragma unroll
  for (int r = 0; r < 4; r++) {
    const int rr = quad * 4 + r;
    rbase[r] = wr * 64 + rr * 64 + lw;
    const int rm = rr & 7;
    xt0[r] = (cb0 ^ rm) << 3;
    xt1[r] = ((cb0 + 2) ^ rm) << 3;
  }

  f32x4 acc[4][4] = {};

  #pragma unroll
  for (int k0i = 0; k0i < 8; k0i++) {
    const int k0 = k0i * 64;
    #pragma unroll
    for (int r = 0; r < 4; r++) glds16(gb[r] + k0, ldb[r]);
    f16x8 w1f0 = *(const f16x8*)(w1b0 + (size_t)k0 * 32);
    f16x8 w1f1 = *(const f16x8*)(w1b1 + (size_t)k0 * 32);
    const float bv0 = b1b0[k0], bv1 = b1b1[k0];
    f32x4 h0[4], h1[4];
    #pragma unroll
    for (int i = 0; i < 4; i++) {
      f32x4 z = {};
      h0[i] = __builtin_amdgcn_mfma_f32_16x16x32_f16(xfr[i], w1f0, z, 0, 0, 0);
      h1[i] = __builtin_amdgcn_mfma_f32_16x16x32_f16(xfr[i], w1f1, z, 0, 0, 0);
    }
    __syncthreads();
    #pragma unroll
    for (int i = 0; i < 4; i++)
      #pragma unroll
      for (int r = 0; r < 4; r++) {
        As[rbase[r] + i * 1024 + xt0[r]] = (f16_t)fmaxf(h0[i][r] + bv0, 0.0f);
        As[rbase[r] + i * 1024 + xt1[r]] = (f16_t)fmaxf(h1[i][r] + bv1, 0.0f);
      }
    __syncthreads();
    #pragma unroll
    for (int ksi = 0; ksi < 2; ksi++) {
      f16x8 af[4], bf[4];
      #pragma unroll
      for (int i = 0; i < 4; i++) af[i] = *ap[i][ksi];
      #pragma unroll
      for (int j = 0; j < 4; j++) bf[j] = *bp[j][ksi];
      #pragma unroll
      for (int i = 0; i < 4; i++)
        #pragma unroll
        for (int j = 0; j < 4; j++)
          acc[i][j] = __builtin_amdgcn_mfma_f32_16x16x32_f16(af[i], bf[j], acc[i][j], 0, 0, 0);
    }
    __syncthreads();
  }
  #pragma unroll
  for (int i = 0; i < 4; i++)
    #pragma unroll
    for (int j = 0; j < 4; j++) {
      const int col = n0 + wc + j * 16 + lm;
      const float bv = b2[col];
      #pragma unroll
      for (int r = 0; r < 4; r++) {
        const int rowi = m0 + wr + i * 16 + quad * 4 + r;
        H2[(size_t)rowi * HID + col] = (f16_t)fmaxf(acc[i][j][r] + bv, 0.0f);
      }
    }
}

// ---------------------------------------------------------------------------
// Fused GEMM3 + spline. Tile 128x96 (4 channels), 8 n-tiles. Single-pass
// epilogue: full 128x96 raw tile stored as F16 (stride 104 -> 26.6 KB, fits
// the As/Bs union), ALL waves dump simultaneously (disjoint quadrants), ONE
// barrier, then each thread runs 2 spline evals (3x ds_read_b128 + cvt).
// ---------------------------------------------------------------------------
#define RSH 104  // f16 rawt stride: row*208B and chl*48B are 16B-aligned
#define SP1 0.5413248546f  // softplus(SP1) == 1

__launch_bounds__(256)
__global__ void gemm3_spline(const f16_t* __restrict__ A, const f16_t* __restrict__ Bt,
                             const float* __restrict__ bias,
                             const void* __restrict__ xorig,
                             void* __restrict__ outv, float* __restrict__ ldp,
                             int M, int r0, const int* __restrict__ flagp) {
  constexpr int BK = 64;
  __shared__ __align__(16) char smem[16384 + 12288];  // 28672 B
  f16_t* As = (f16_t*)smem;                 // 128*64*2
  f16_t* Bs = (f16_t*)(smem + 16384);       //  96*64*2
  f16_t* rawh = (f16_t*)smem;               // 128 x 104 f16 = 26624 B

  const int t = threadIdx.x;
  const int id = blockIdx.x;
  const int xcd = id & 7, s = id >> 3;
  const int ntile = s & 7;
  const int m0 = ((s >> 3) * 8 + xcd) * 128;
  const int n0 = ntile * 96;
  const int lrow = t >> 3, lcb = t & 7;
  const int lane = t & 63, w = t >> 6;
  const int wr = (w >> 1) * 64, wc = (w & 1) * 48;
  const int lm = lane & 15, quad = lane >> 4;
  const int flag = *flagp;

  // Prefetch x for both evals (miss latency hides behind the K-loop)
  const int prow = t >> 2, pch = ntile * 4 + (t & 3);
  float xt_pre[2];
  #pragma unroll
  for (int e = 0; e < 2; e++) {
    const size_t gi = (size_t)(r0 + m0 + e * 64 + prow) * 64 + 32 + pch;
    xt_pre[e] = flag ? ((const float*)xorig)[gi] : (float)((const bf16_t*)xorig)[gi];
  }

  const f16_t* ga[4];
  const f16_t* gb[3];
  f16_t* lda[4];
  f16_t* ldb[3];
  #pragma unroll
  for (int r = 0; r < 4; r++) {
    const int row = r * 32 + lrow;
    const int gc = (lcb ^ (row & 7)) * 8;
    ga[r] = A + (size_t)(m0 + row) * 512 + gc;
    lda[r] = &As[row * BK + lcb * 8];
  }
  #pragma unroll
  for (int r = 0; r < 3; r++) {
    const int row = r * 32 + lrow;
    const int gc = (lcb ^ (row & 7)) * 8;
    gb[r] = Bt + (size_t)(n0 + row) * 512 + gc;
    ldb[r] = &Bs[row * BK + lcb * 8];
  }
  const f16x8* ap[4][2];
  const f16x8* bp[3][2];
  #pragma unroll
  for (int ksi = 0; ksi < 2; ksi++) {
    const int qb = ksi * 4 + quad;
    #pragma unroll
    for (int i = 0; i < 4; i++) {
      const int ra = wr + i * 16 + lm;
      ap[i][ksi] = (const f16x8*)&As[ra * BK + ((qb ^ (ra & 7)) << 3)];
    }
    #pragma unroll
    for (int j = 0; j < 3; j++) {
      const int rb = wc + j * 16 + lm;
      bp[j][ksi] = (const f16x8*)&Bs[rb * BK + ((qb ^ (rb & 7)) << 3)];
    }
  }

  f32x4 acc[4][3] = {};

  #pragma unroll
  for (int k0 = 0; k0 < 512; k0 += BK) {
    #pragma unroll
    for (int r = 0; r < 4; r++) glds16(ga[r] + k0, lda[r]);
    #pragma unroll
    for (int r = 0; r < 3; r++) glds16(gb[r] + k0, ldb[r]);
    __syncthreads();
    #pragma unroll
    for (int ksi = 0; ksi < 2; ksi++) {
      f16x8 af[4], bf[3];
      #pragma unroll
      for (int i = 0; i < 4; i++) af[i] = *ap[i][ksi];
      #pragma unroll
      for (int j = 0; j < 3; j++) bf[j] = *bp[j][ksi];
      #pragma unroll
      for (int i = 0; i < 4; i++)
        #pragma unroll
        for (int j = 0; j < 3; j++)
          acc[i][j] = __builtin_amdgcn_mfma_f32_16x16x32_f16(af[i], bf[j], acc[i][j], 0, 0, 0);
    }
    __syncthreads();
  }

  // All waves dump their acc quadrant (+bias) as f16 -- disjoint regions.
  #pragma unroll
  for (int i = 0; i < 4; i++)
    #pragma unroll
    for (int j = 0; j < 3; j++) {
      const int col = wc + j * 16 + lm;
      const float bv = bias[n0 + col];
      #pragma unroll
      for (int r = 0; r < 4; r++)
        rawh[(wr + i * 16 + quad * 4 + r) * RSH + col] = (f16_t)(acc[i][j][r] + bv);
    }
  __syncthreads();

  #pragma unroll
  for (int e = 0; e < 2; e++) {
    const int row = e * 64 + prow;
    const f16_t* c16 = &rawh[row * RSH + (t & 3) * 24];
    const f16x8 v0 = *(const f16x8*)(c16);
    const f16x8 v1 = *(const f16x8*)(c16 + 8);
    const f16x8 v2 = *(const f16x8*)(c16 + 16);
    float wa[8], ha[8], da[7];
    #pragma unroll
    for (int j = 0; j < 8; j++) { wa[j] = (float)v0[j]; ha[j] = (float)v1[j]; }
    #pragma unroll
    for (int j = 0; j < 7; j++) da[j] = (float)v2[j];

    const float xt = xt_pre[e];
    const bool inside = (xt >= -TAILB) && (xt <= TAILB);
    const float xc = fminf(fmaxf(xt, -TAILB + 1e-6f), TAILB - 1e-6f);

    float mw = wa[0], mh = ha[0];
    #pragma unroll
    for (int j = 1; j < 8; j++) { mw = fmaxf(mw, wa[j]); mh = fmaxf(mh, ha[j]); }
    float ew[8], eh[8], sew = 0.f, seh = 0.f;
    #pragma unroll
    for (int j = 0; j < 8; j++) {
      ew[j] = __expf(wa[j] - mw); sew += ew[j];
      eh[j] = __expf(ha[j] - mh); seh += eh[j];
    }
    const float wsc = 6.0f * frcp(sew), hsc = 6.0f * frcp(seh);
    #pragma unroll
    for (int j = 0; j < 8; j++) { ew[j] *= wsc; eh[j] *= hsc; }

    float accw = -TAILB, runh = -TAILB;
    float cwk = -TAILB, chk = -TAILB;
    float wk = ew[0], hk = eh[0];
    float dkr = SP1, dk1r = da[0];
    #pragma unroll
    for (int i = 0; i < 7; i++) {
      accw += ew[i];
      runh += eh[i];
      const bool cond = accw < xc;
      cwk  = cond ? accw : cwk;
      chk  = cond ? runh : chk;
      wk   = cond ? ew[i + 1] : wk;
      hk   = cond ? eh[i + 1] : hk;
      dkr  = cond ? da[i] : dkr;
      dk1r = cond ? ((i == 6) ? SP1 : da[i + 1]) : dk1r;
    }
    const float dk  = fmaxf(dkr, 0.0f)  + __logf(1.0f + __expf(-fabsf(dkr)));
    const float dk1 = fmaxf(dk1r, 0.0f) + __logf(1.0f + __expf(-fabsf(dk1r)));

    const float rwk = frcp(wk);
    float xi = (xc - cwk) * rwk;
    xi = fminf(fmaxf(xi, 1e-6f), 1.0f - 1e-6f);
    const float om = 1.0f - xi;
    const float sl = hk * rwk;
    const float num = hk * (sl * xi * xi + dk * xi * om);
    const float den = sl + (dk + dk1 - 2.0f * sl) * xi * om;
    const float y_in = chk + num * frcp(den);
    const float t1 = sl * sl * (dk1 * xi * xi + 2.0f * sl * xi * om + dk * om * om);
    const float ld_in = __logf(t1 + 1e-8f) - __logf(den * den + 1e-8f);

    const float yv = inside ? y_in : xt;
    const float ldv = inside ? ld_in : 0.0f;

    const size_t grow = (size_t)(r0 + m0 + row);
    if (flag) ((float*)outv)[grow * 64 + 32 + pch] = yv;
    else      ((bf16_t*)outv)[grow * 64 + 32 + pch] = (bf16_t)yv;

    float l = ldv + __shfl_down(ldv, 1, 4);
    l += __shfl_down(l, 2, 4);
    if ((t & 3) == 0) ldp[(size_t)ntile * M + grow] = l;
  }
}

// ---------------------------------------------------------------------------
extern "C" void kernel_launch(void* const* d_in, const int* in_sizes, int n_in,
                              void* d_out, int out_size, void* d_ws, size_t ws_size,
                              hipStream_t stream) {
  const void* x  = d_in[0];
  const void* W1 = d_in[1];
  const void* b1 = d_in[2];
  const void* W2 = d_in[3];
  const void* b2 = d_in[4];
  const void* W3 = d_in[5];
  const void* b3 = d_in[6];
  const int M = in_sizes[0] / 64;  // 131072

  char* ws = (char*)d_ws;
  size_t off = 0;
  auto alloc = [&](size_t bytes) {
    void* p = ws + off;
    off += (bytes + 255) & ~(size_t)255;
    return p;
  };
  int*   flag = (int*)alloc(256);
  float* bf1  = (float*)alloc(512 * 4);
  float* bf2  = (float*)alloc(512 * 4);
  float* bf3  = (float*)alloc(NRAW_PAD * 4);
  f16_t* W1t  = (f16_t*)alloc((size_t)512 * 32 * 2);
  f16_t* W2t  = (f16_t*)alloc((size_t)512 * 512 * 2);
  f16_t* W3t  = (f16_t*)alloc((size_t)NRAW_PAD * 512 * 2);
  f16_t* xf   = (f16_t*)alloc((size_t)M * 32 * 2);
  float* ldp  = (float*)alloc((size_t)8 * M * 4);

  // Only h2 lives in ws. rows % 1024 == 0 (XCD swizzle needs mt % 8).
  const size_t per_row = (size_t)HID * 2;
  size_t avail = (ws_size > off + 4096) ? (ws_size - off - 4096) : 0;
  long rows = (long)(avail / per_row);
  rows -= rows % 1024;
  if (rows > M) rows = M;
  if (rows < 1024) rows = 1024;

  f16_t* h2 = (f16_t*)alloc((size_t)rows * HID * 2);

  detect_dtype<<<1, 256, 0, stream>>>(x, flag);
  conv_wb<<<2631, 256, 0, stream>>>(W1, W2, W3, b1, b2, b3,
                                    W1t, W2t, W3t, bf1, bf2, bf3, flag);
  convert_x<<<(M * 32 / 8 + 255) / 256, 256, 0, stream>>>(x, xf, d_out, flag, M * 32);

  for (int r0 = 0; r0 < M; r0 += (int)rows) {
    const int mc = (int)((M - r0 < rows) ? (M - r0) : rows);
    const int mt = mc / 128;
    gemm12<<<mt * 4, 256, 0, stream>>>(
        xf + (size_t)r0 * 32, W1t, bf1, W2t, bf2, h2);
    gemm3_spline<<<mt * 8, 256, 0, stream>>>(
        h2, W3t, bf3, x, d_out, ldp, M, r0, flag);
  }
  ld_finalize<<<(M + 255) / 256, 256, 0, stream>>>(ldp, d_out, flag, M);
}

// Round 13
// 340.673 us; speedup vs baseline: 1.0829x; 1.0829x over previous
//
#include <hip/hip_runtime.h>
#include <hip/hip_bf16.h>
#include <stdint.h>

typedef __bf16 bf16_t;
typedef _Float16 f16_t;
typedef _Float16 f16x8 __attribute__((ext_vector_type(8)));
typedef _Float16 f16x4 __attribute__((ext_vector_type(4)));
typedef float f32x4 __attribute__((ext_vector_type(4)));

#define HID 512
#define NRAW 736      // 32 * 23 (source layout)
#define NRAW_PAD 768  // 32 * 24 (channel-aligned: 23 coeffs + 1 zero pad)
#define TAILB 3.0f

__device__ __forceinline__ void glds16(const void* g, void* s) {
  __builtin_amdgcn_global_load_lds(
      (const __attribute__((address_space(1))) void*)g,
      (__attribute__((address_space(3))) void*)s, 16, 0, 0);
}
__device__ __forceinline__ float frcp(float x) { return __builtin_amdgcn_rcpf(x); }

// ---------------------------------------------------------------------------
__global__ void detect_dtype(const void* x, int* flag) {
  __shared__ int s;
  if (threadIdx.x == 0) s = 0;
  __syncthreads();
  const bf16_t* xb = (const bf16_t*)x;
  int cnt = 0;
  for (int j = 0; j < 16; j++) {
    float v = (float)xb[threadIdx.x * 16 + j];
    if (!(v == v) || fabsf(v) > 64.0f) cnt++;
  }
  atomicAdd(&s, cnt);
  __syncthreads();
  if (threadIdx.x == 0) *flag = (s > 64) ? 1 : 0;
}

// ---------------------------------------------------------------------------
__global__ void conv_wb(const void* W1, const void* W2, const void* W3,
                        const void* b1, const void* b2, const void* b3,
                        f16_t* __restrict__ w1t, f16_t* __restrict__ w2t,
                        f16_t* __restrict__ w3t,
                        float* __restrict__ bf1, float* __restrict__ bf2,
                        float* __restrict__ bf3, const int* flagp) {
  const int flag = *flagp;
  auto rd = [&](const void* p, size_t idx) -> float {
    return flag ? ((const float*)p)[idx] : (float)((const bf16_t*)p)[idx];
  };
  int i = blockIdx.x * 256 + threadIdx.x;
  if (i < 512 * 32)  { w1t[i] = (f16_t)rd(W1, (size_t)(i & 31) * 512 + (i >> 5)); return; }
  i -= 512 * 32;
  if (i < 512 * 512) { w2t[i] = (f16_t)rd(W2, (size_t)(i & 511) * 512 + (i >> 9)); return; }
  i -= 512 * 512;
  if (i < NRAW_PAD * 512) {
    int n = i >> 9, k = i & 511;
    int ch = n / 24, e = n % 24;
    w3t[i] = (e < 23) ? (f16_t)rd(W3, (size_t)k * NRAW + ch * 23 + e) : (f16_t)0.0f;
    return;
  }
  i -= NRAW_PAD * 512;
  if (i < 512) { bf1[i] = rd(b1, i); return; }
  i -= 512;
  if (i < 512) { bf2[i] = rd(b2, i); return; }
  i -= 512;
  if (i < NRAW_PAD) {
    int ch = i / 24, e = i % 24;
    bf3[i] = (e < 23) ? rd(b3, (size_t)ch * 23 + e) : 0.0f;
  }
}

// Masked passthrough only: out[:, :32] = x[:, :32] (same dtype, raw copy).
__global__ void convert_x(const void* x, void* __restrict__ outv,
                          const int* flagp, int n) {
  const int flag = *flagp;
  const int i0 = (blockIdx.x * 256 + threadIdx.x) * 8;
  if (i0 >= n) return;
  const int row = i0 >> 5, col = i0 & 31;
  const size_t src = (size_t)row * 64 + col;
  if (flag) {
    const float4* s4 = (const float4*)((const float*)x + src);
    float4* d4 = (float4*)((float*)outv + src);
    d4[0] = s4[0]; d4[1] = s4[1];
  } else {
    *(uint4*)((bf16_t*)outv + src) = *(const uint4*)((const bf16_t*)x + src);
  }
}

__global__ void ld_finalize(const float* __restrict__ ldp, void* __restrict__ outv,
                            const int* __restrict__ flagp, int M) {
  const int i = blockIdx.x * 256 + threadIdx.x;
  if (i >= M) return;
  float s = 0.f;
  #pragma unroll
  for (int n = 0; n < 8; n++) s += ldp[(size_t)n * M + i];
  if (*flagp) ((float*)outv)[(size_t)M * 64 + i] = s;
  else        ((bf16_t*)outv)[(size_t)M * 64 + i] = (bf16_t)s;
}

// ---------------------------------------------------------------------------
// Fused GEMM1+GEMM2: h2 = relu(relu(X@W1+b1)@W2+b2). X read directly from
// xorig. h1 produced TRANSPOSED via mfma(w1frag, xfrag): lane holds 4
// consecutive h1-cols for one X-row -> 8 ds_write_b64 per thread/iter.
// 3 barriers/iter: the END barrier is REQUIRED -- it keeps a fast wave's
// next-iteration glds16(Bs) from landing while slow waves still ds_read Bs
// (removing it corrupted h2 intermittently in round 12).
// ---------------------------------------------------------------------------
__launch_bounds__(256)
__global__ void gemm12(const void* __restrict__ xorig, const f16_t* __restrict__ W1t,
                       const float* __restrict__ b1, const f16_t* __restrict__ W2t,
                       const float* __restrict__ b2, f16_t* __restrict__ H2,
                       int r0, const int* __restrict__ flagp) {
  constexpr int BK = 64;
  __shared__ __align__(16) f16_t As[128 * BK], Bs[128 * BK];
  const int t = threadIdx.x;
  const int id = blockIdx.x;
  const int xcd = id & 7, s = id >> 3;
  const int n0 = (s & 3) * 128;
  const int m0 = ((s >> 2) * 8 + xcd) * 128;
  const int lrow = t >> 3, lcb = t & 7;
  const int lane = t & 63, w = t >> 6;
  const int wr = (w >> 1) * 64, wc = (w & 1) * 64, wc2 = (w & 1) * 32;
  const int lm = lane & 15, quad = lane >> 4;
  const int flag = *flagp;

  // W2t staging
  const f16_t* gb[4];
  f16_t* ldb[4];
  #pragma unroll
  for (int r = 0; r < 4; r++) {
    const int row = r * 32 + lrow;
    const int gc = (lcb ^ (row & 7)) * 8;
    gb[r] = W2t + (size_t)(n0 + row) * 512 + gc;
    ldb[r] = &Bs[row * BK + lcb * 8];
  }
  // fragment read pointers
  const f16x8* ap[4][2];
  const f16x8* bp[4][2];
  #pragma unroll
  for (int i = 0; i < 4; i++) {
    const int ra = wr + i * 16 + lm, rb = wc + i * 16 + lm;
    #pragma unroll
    for (int ksi = 0; ksi < 2; ksi++) {
      const int qb = ksi * 4 + quad;
      ap[i][ksi] = (const f16x8*)&As[ra * BK + ((qb ^ (ra & 7)) << 3)];
      bp[i][ksi] = (const f16x8*)&Bs[rb * BK + ((qb ^ (rb & 7)) << 3)];
    }
  }
  // X fragments (B operand of h-mfma): Xrow = r0+m0+wr+i*16+lm, Xcol = quad*8+j
  f16x8 xfr[4];
  #pragma unroll
  for (int i = 0; i < 4; i++) {
    const size_t xrow = (size_t)(r0 + m0 + wr + i * 16 + lm);
    if (flag) {
      const float* px = (const float*)xorig + xrow * 64 + quad * 8;
      const float4 a = *(const float4*)px;
      const float4 b = *(const float4*)(px + 4);
      f16x8 v;
      v[0] = (f16_t)a.x; v[1] = (f16_t)a.y; v[2] = (f16_t)a.z; v[3] = (f16_t)a.w;
      v[4] = (f16_t)b.x; v[5] = (f16_t)b.y; v[6] = (f16_t)b.z; v[7] = (f16_t)b.w;
      xfr[i] = v;
    } else {
      const bf16_t* px = (const bf16_t*)xorig + xrow * 64 + quad * 8;
      f16x8 v;
      #pragma unroll
      for (int j = 0; j < 8; j++) v[j] = (f16_t)(float)px[j];
      xfr[i] = v;
    }
  }
  // W1 A-frag pointers (h1col = k0 + wc2 + 16*Tl + lm, k = quad*8+j)
  const f16_t* w1p0 = W1t + (size_t)(wc2 + lm) * 32 + quad * 8;
  const f16_t* w1p1 = W1t + (size_t)(wc2 + 16 + lm) * 32 + quad * 8;
  // bias float4 (b1[k0 + wc2 + 16Tl + 4q + r])
  const float* b1p0 = b1 + wc2 + 4 * quad;
  const float* b1p1 = b1 + wc2 + 16 + 4 * quad;
  // As write addrs (k0-invariant): elem = row*64 + ((cb^(row&7))<<3) + 4*(q&1)
  f16_t* wadr[4][2];
  #pragma unroll
  for (int i = 0; i < 4; i++) {
    const int row = wr + i * 16 + lm;
    #pragma unroll
    for (int Tl = 0; Tl < 2; Tl++) {
      const int cb = (wc2 >> 3) + 2 * Tl + (quad >> 1);
      wadr[i][Tl] = &As[row * BK + ((cb ^ (row & 7)) << 3) + 4 * (quad & 1)];
    }
  }

  f32x4 acc[4][4] = {};
  f16x8 w1f0 = *(const f16x8*)w1p0;
  f16x8 w1f1 = *(const f16x8*)w1p1;

  #pragma unroll
  for (int k0i = 0; k0i < 8; k0i++) {
    const int k0 = k0i * 64;
    #pragma unroll
    for (int r = 0; r < 4; r++) glds16(gb[r] + k0, ldb[r]);
    const float4 bv0 = *(const float4*)(b1p0 + k0);
    const float4 bv1 = *(const float4*)(b1p1 + k0);
    f32x4 h[4][2];
    #pragma unroll
    for (int i = 0; i < 4; i++) {
      f32x4 z = {};
      h[i][0] = __builtin_amdgcn_mfma_f32_16x16x32_f16(w1f0, xfr[i], z, 0, 0, 0);
      h[i][1] = __builtin_amdgcn_mfma_f32_16x16x32_f16(w1f1, xfr[i], z, 0, 0, 0);
    }
    if (k0i < 7) {  // software-pipeline next chunk's W1 frags
      w1f0 = *(const f16x8*)(w1p0 + (size_t)(k0 + 64) * 32);
      w1f1 = *(const f16x8*)(w1p1 + (size_t)(k0 + 64) * 32);
    }
    __syncthreads();  // prior GEMM2-phase As reads complete before overwrite
    #pragma unroll
    for (int i = 0; i < 4; i++) {
      f16x4 v0, v1;
      v0[0] = (f16_t)fmaxf(h[i][0][0] + bv0.x, 0.0f);
      v0[1] = (f16_t)fmaxf(h[i][0][1] + bv0.y, 0.0f);
      v0[2] = (f16_t)fmaxf(h[i][0][2] + bv0.z, 0.0f);
      v0[3] = (f16_t)fmaxf(h[i][0][3] + bv0.w, 0.0f);
      v1[0] = (f16_t)fmaxf(h[i][1][0] + bv1.x, 0.0f);
      v1[1] = (f16_t)fmaxf(h[i][1][1] + bv1.y, 0.0f);
      v1[2] = (f16_t)fmaxf(h[i][1][2] + bv1.z, 0.0f);
      v1[3] = (f16_t)fmaxf(h[i][1][3] + bv1.w, 0.0f);
      *(f16x4*)wadr[i][0] = v0;
      *(f16x4*)wadr[i][1] = v1;
    }
    __syncthreads();  // As visible; Bs glds16 drained (barrier implies vmcnt 0)
    #pragma unroll
    for (int ksi = 0; ksi < 2; ksi++) {
      f16x8 af[4], bf[4];
      #pragma unroll
      for (int i = 0; i < 4; i++) af[i] = *ap[i][ksi];
      #pragma unroll
      for (int j = 0; j < 4; j++) bf[j] = *bp[j][ksi];
      #pragma unroll
      for (int i = 0; i < 4; i++)
        #pragma unroll
        for (int j = 0; j < 4; j++)
          acc[i][j] = __builtin_amdgcn_mfma_f32_16x16x32_f16(af[i], bf[j], acc[i][j], 0, 0, 0);
    }
    if (k0i < 7) __syncthreads();  // REQUIRED: next iter's glds16(Bs) must not
                                   // land while other waves still read Bs
  }
  #pragma unroll
  for (int i = 0; i < 4; i++)
    #pragma unroll
    for (int j = 0; j < 4; j++) {
      const int col = n0 + wc + j * 16 + lm;
      const float bv = b2[col];
      #pragma unroll
      for (int r = 0; r < 4; r++) {
        const int rowi = m0 + wr + i * 16 + quad * 4 + r;
        H2[(size_t)rowi * HID + col] = (f16_t)fmaxf(acc[i][j][r] + bv, 0.0f);
      }
    }
}

// ---------------------------------------------------------------------------
// Fused GEMM3 + spline (unchanged from round 11).
// ---------------------------------------------------------------------------
#define RSH 104
#define SP1 0.5413248546f  // softplus(SP1) == 1

__launch_bounds__(256)
__global__ void gemm3_spline(const f16_t* __restrict__ A, const f16_t* __restrict__ Bt,
                             const float* __restrict__ bias,
                             const void* __restrict__ xorig,
                             void* __restrict__ outv, float* __restrict__ ldp,
                             int M, int r0, const int* __restrict__ flagp) {
  constexpr int BK = 64;
  __shared__ __align__(16) char smem[16384 + 12288];
  f16_t* As = (f16_t*)smem;
  f16_t* Bs = (f16_t*)(smem + 16384);
  f16_t* rawh = (f16_t*)smem;  // 128 x 104 f16 (post K-loop)

  const int t = threadIdx.x;
  const int id = blockIdx.x;
  const int xcd = id & 7, s = id >> 3;
  const int ntile = s & 7;
  const int m0 = ((s >> 3) * 8 + xcd) * 128;
  const int n0 = ntile * 96;
  const int lrow = t >> 3, lcb = t & 7;
  const int lane = t & 63, w = t >> 6;
  const int wr = (w >> 1) * 64, wc = (w & 1) * 48;
  const int lm = lane & 15, quad = lane >> 4;
  const int flag = *flagp;

  const int prow = t >> 2, pch = ntile * 4 + (t & 3);
  float xt_pre[2];
  #pragma unroll
  for (int e = 0; e < 2; e++) {
    const size_t gi = (size_t)(r0 + m0 + e * 64 + prow) * 64 + 32 + pch;
    xt_pre[e] = flag ? ((const float*)xorig)[gi] : (float)((const bf16_t*)xorig)[gi];
  }

  const f16_t* ga[4];
  const f16_t* gb[3];
  f16_t* lda[4];
  f16_t* ldb[3];
  #pragma unroll
  for (int r = 0; r < 4; r++) {
    const int row = r * 32 + lrow;
    const int gc = (lcb ^ (row & 7)) * 8;
    ga[r] = A + (size_t)(m0 + row) * 512 + gc;
    lda[r] = &As[row * BK + lcb * 8];
  }
  #pragma unroll
  for (int r = 0; r < 3; r++) {
    const int row = r * 32 + lrow;
    const int gc = (lcb ^ (row & 7)) * 8;
    gb[r] = Bt + (size_t)(n0 + row) * 512 + gc;
    ldb[r] = &Bs[row * BK + lcb * 8];
  }
  const f16x8* ap[4][2];
  const f16x8* bp[3][2];
  #pragma unroll
  for (int ksi = 0; ksi < 2; ksi++) {
    const int qb = ksi * 4 + quad;
    #pragma unroll
    for (int i = 0; i < 4; i++) {
      const int ra = wr + i * 16 + lm;
      ap[i][ksi] = (const f16x8*)&As[ra * BK + ((qb ^ (ra & 7)) << 3)];
    }
    #pragma unroll
    for (int j = 0; j < 3; j++) {
      const int rb = wc + j * 16 + lm;
      bp[j][ksi] = (const f16x8*)&Bs[rb * BK + ((qb ^ (rb & 7)) << 3)];
    }
  }

  f32x4 acc[4][3] = {};

  #pragma unroll
  for (int k0 = 0; k0 < 512; k0 += BK) {
    #pragma unroll
    for (int r = 0; r < 4; r++) glds16(ga[r] + k0, lda[r]);
    #pragma unroll
    for (int r = 0; r < 3; r++) glds16(gb[r] + k0, ldb[r]);
    __syncthreads();
    #pragma unroll
    for (int ksi = 0; ksi < 2; ksi++) {
      f16x8 af[4], bf[3];
      #pragma unroll
      for (int i = 0; i < 4; i++) af[i] = *ap[i][ksi];
      #pragma unroll
      for (int j = 0; j < 3; j++) bf[j] = *bp[j][ksi];
      #pragma unroll
      for (int i = 0; i < 4; i++)
        #pragma unroll
        for (int j = 0; j < 3; j++)
          acc[i][j] = __builtin_amdgcn_mfma_f32_16x16x32_f16(af[i], bf[j], acc[i][j], 0, 0, 0);
    }
    __syncthreads();
  }

  #pragma unroll
  for (int i = 0; i < 4; i++)
    #pragma unroll
    for (int j = 0; j < 3; j++) {
      const int col = wc + j * 16 + lm;
      const float bv = bias[n0 + col];
      #pragma unroll
      for (int r = 0; r < 4; r++)
        rawh[(wr + i * 16 + quad * 4 + r) * RSH + col] = (f16_t)(acc[i][j][r] + bv);
    }
  __syncthreads();

  #pragma unroll
  for (int e = 0; e < 2; e++) {
    const int row = e * 64 + prow;
    const f16_t* c16 = &rawh[row * RSH + (t & 3) * 24];
    const f16x8 v0 = *(const f16x8*)(c16);
    const f16x8 v1 = *(const f16x8*)(c16 + 8);
    const f16x8 v2 = *(const f16x8*)(c16 + 16);
    float wa[8], ha[8], da[7];
    #pragma unroll
    for (int j = 0; j < 8; j++) { wa[j] = (float)v0[j]; ha[j] = (float)v1[j]; }
    #pragma unroll
    for (int j = 0; j < 7; j++) da[j] = (float)v2[j];

    const float xt = xt_pre[e];
    const bool inside = (xt >= -TAILB) && (xt <= TAILB);
    const float xc = fminf(fmaxf(xt, -TAILB + 1e-6f), TAILB - 1e-6f);

    float mw = wa[0], mh = ha[0];
    #pragma unroll
    for (int j = 1; j < 8; j++) { mw = fmaxf(mw, wa[j]); mh = fmaxf(mh, ha[j]); }
    float ew[8], eh[8], sew = 0.f, seh = 0.f;
    #pragma unroll
    for (int j = 0; j < 8; j++) {
      ew[j] = __expf(wa[j] - mw); sew += ew[j];
      eh[j] = __expf(ha[j] - mh); seh += eh[j];
    }
    const float wsc = 6.0f * frcp(sew), hsc = 6.0f * frcp(seh);
    #pragma unroll
    for (int j = 0; j < 8; j++) { ew[j] *= wsc; eh[j] *= hsc; }

    float accw = -TAILB, runh = -TAILB;
    float cwk = -TAILB, chk = -TAILB;
    float wk = ew[0], hk = eh[0];
    float dkr = SP1, dk1r = da[0];
    #pragma unroll
    for (int i = 0; i < 7; i++) {
      accw += ew[i];
      runh += eh[i];
      const bool cond = accw < xc;
      cwk  = cond ? accw : cwk;
      chk  = cond ? runh : chk;
      wk   = cond ? ew[i + 1] : wk;
      hk   = cond ? eh[i + 1] : hk;
      dkr  = cond ? da[i] : dkr;
      dk1r = cond ? ((i == 6) ? SP1 : da[i + 1]) : dk1r;
    }
    const float dk  = fmaxf(dkr, 0.0f)  + __logf(1.0f + __expf(-fabsf(dkr)));
    const float dk1 = fmaxf(dk1r, 0.0f) + __logf(1.0f + __expf(-fabsf(dk1r)));

    const float rwk = frcp(wk);
    float xi = (xc - cwk) * rwk;
    xi = fminf(fmaxf(xi, 1e-6f), 1.0f - 1e-6f);
    const float om = 1.0f - xi;
    const float sl = hk * rwk;
    const float num = hk * (sl * xi * xi + dk * xi * om);
    const float den = sl + (dk + dk1 - 2.0f * sl) * xi * om;
    const float y_in = chk + num * frcp(den);
    const float t1 = sl * sl * (dk1 * xi * xi + 2.0f * sl * xi * om + dk * om * om);
    const float ld_in = __logf(t1 + 1e-8f) - __logf(den * den + 1e-8f);

    const float yv = inside ? y_in : xt;
    const float ldv = inside ? ld_in : 0.0f;

    const size_t grow = (size_t)(r0 + m0 + row);
    if (flag) ((float*)outv)[grow * 64 + 32 + pch] = yv;
    else      ((bf16_t*)outv)[grow * 64 + 32 + pch] = (bf16_t)yv;

    float l = ldv + __shfl_down(ldv, 1, 4);
    l += __shfl_down(l, 2, 4);
    if ((t & 3) == 0) ldp[(size_t)ntile * M + grow] = l;
  }
}

// ---------------------------------------------------------------------------
extern "C" void kernel_launch(void* const* d_in, const int* in_sizes, int n_in,
                              void* d_out, int out_size, void* d_ws, size_t ws_size,
                              hipStream_t stream) {
  const void* x  = d_in[0];
  const void* W1 = d_in[1];
  const void* b1 = d_in[2];
  const void* W2 = d_in[3];
  const void* b2 = d_in[4];
  const void* W3 = d_in[5];
  const void* b3 = d_in[6];
  const int M = in_sizes[0] / 64;  // 131072

  char* ws = (char*)d_ws;
  size_t off = 0;
  auto alloc = [&](size_t bytes) {
    void* p = ws + off;
    off += (bytes + 255) & ~(size_t)255;
    return p;
  };
  int*   flag = (int*)alloc(256);
  float* bf1  = (float*)alloc(512 * 4);
  float* bf2  = (float*)alloc(512 * 4);
  float* bf3  = (float*)alloc(NRAW_PAD * 4);
  f16_t* W1t  = (f16_t*)alloc((size_t)512 * 32 * 2);
  f16_t* W2t  = (f16_t*)alloc((size_t)512 * 512 * 2);
  f16_t* W3t  = (f16_t*)alloc((size_t)NRAW_PAD * 512 * 2);
  float* ldp  = (float*)alloc((size_t)8 * M * 4);

  // Only h2 lives in ws. rows % 1024 == 0 (XCD swizzle needs mt % 8).
  const size_t per_row = (size_t)HID * 2;
  size_t avail = (ws_size > off + 4096) ? (ws_size - off - 4096) : 0;
  long rows = (long)(avail / per_row);
  rows -= rows % 1024;
  if (rows > M) rows = M;
  if (rows < 1024) rows = 1024;

  f16_t* h2 = (f16_t*)alloc((size_t)rows * HID * 2);

  detect_dtype<<<1, 256, 0, stream>>>(x, flag);
  conv_wb<<<2631, 256, 0, stream>>>(W1, W2, W3, b1, b2, b3,
                                    W1t, W2t, W3t, bf1, bf2, bf3, flag);
  convert_x<<<(M * 32 / 8 + 255) / 256, 256, 0, stream>>>(x, d_out, flag, M * 32);

  for (int r0 = 0; r0 < M; r0 += (int)rows) {
    const int mc = (int)((M - r0 < rows) ? (M - r0) : rows);
    const int mt = mc / 128;
    gemm12<<<mt * 4, 256, 0, stream>>>(x, W1t, bf1, W2t, bf2, h2, r0, flag);
    gemm3_spline<<<mt * 8, 256, 0, stream>>>(
        h2, W3t, bf3, x, d_out, ldp, M, r0, flag);
  }
  ld_finalize<<<(M + 255) / 256, 256, 0, stream>>>(ldp, d_out, flag, M);
}